// Round 1
// 384.805 us; speedup vs baseline: 1.0195x; 1.0195x over previous
//
#include <hip/hip_runtime.h>

// Problem constants (fixed by reference setup_inputs)
#define B   4
#define C   64      // input channels
#define D   64      // dims per head of q/k/v
#define NN  25      // angRes*angRes angular positions
#define HW  4096    // h*w
#define F   (D*HW)  // 262144 feature dim (d,h,w) flattened

#define SW  256     // f elems per wave in k_sqk (4 waves/block) -> 1024 blocks

typedef unsigned short ushort_t;
typedef unsigned int   uint_t;
typedef __attribute__((ext_vector_type(8)))  short  short8;   // 8 bf16 (4 VGPRs)
typedef __attribute__((ext_vector_type(16))) float  floatx16; // MFMA 32x32 accum
typedef __attribute__((ext_vector_type(4)))  float  f32x4;    // indexable float4
typedef __attribute__((ext_vector_type(4)))  unsigned short us4;

// Transposed weights: Wt[c][d'] = W[d'][c] (d'<128: q rows then k rows),
// Wvt[c][d] = W[128+d][c]. Tiny, rewritten every launch (same work per call).
__device__ float g_Wt[C * 128];
__device__ float g_Wvt[C * 64];

static __device__ __forceinline__ ushort_t f2bf(float f) {
    uint_t u = __float_as_uint(f);
    u += 0x7FFFu + ((u >> 16) & 1u);   // round-to-nearest-even
    return (ushort_t)(u >> 16);
}

// ---- K0: zero the S/qq/kk accumulators (they live at head of d_out) ----
__global__ void k_zero(float* acc) {
    int i = blockIdx.x * 256 + threadIdx.x;
    if (i < 2700) acc[i] = 0.f;   // S 2500 + qq 100 + kk 100
}

// ---- Kw: transpose W into g_Wt / g_Wvt. 48 blocks x 256 thr. ----
__global__ void k_wprep(const float* __restrict__ W) {
    int i = blockIdx.x * 256 + threadIdx.x;          // over 192*64
    if (i < 128 * 64) {
        int dp = i >> 6, c = i & 63;
        g_Wt[c * 128 + dp] = W[dp * 64 + c];
    } else if (i < 192 * 64) {
        int j = i - 128 * 64;
        int d = j >> 6, c = j & 63;
        g_Wvt[c * 64 + d] = W[(128 + d) * 64 + c];
    }
}

// ---- K1: Q,K projection + fused norms, wave-split form.
// grid (HW/256, NN*2, B), 256 thr = 4 waves. blockIdx.y = n*2 + half
// (half 0 = q rows 0..63, half 1 = k rows 64..127). Each wave owns 16
// output rows (dp0 = half*64 + wv*16) and 4 p-columns per lane:
//   acc[16][4] = 64 VGPRs, x loaded as float4.
// W feed per c-iter is ONE s_load_dwordx16 (16 contiguous floats, uniform
// via readfirstlane(wv)) -> double-bufferable in SGPRs, unlike the old
// 128-floats/c form that overflowed the SGPR file and serialized.
__global__ void __launch_bounds__(256, 4)
k_qkproj(const float* __restrict__ x,
         ushort_t* __restrict__ Q, ushort_t* __restrict__ K,
         float* __restrict__ qq, float* __restrict__ kk) {
    const int t    = threadIdx.x;
    const int wv   = __builtin_amdgcn_readfirstlane(t >> 6);  // force SGPR
    const int ln   = t & 63;
    const int half = blockIdx.y & 1;
    const int n    = blockIdx.y >> 1;
    const int b    = blockIdx.z;
    const int p    = blockIdx.x * 256 + ln * 4;
    const int dp0  = half * 64 + wv * 16;          // 16 rows of Wt this wave

    const float* xb = x + ((size_t)(b * C) * NN + n) * HW + p; // x[b][c][n][p]

    float acc[16][4];
#pragma unroll
    for (int i = 0; i < 16; ++i)
#pragma unroll
        for (int j = 0; j < 4; ++j) acc[i][j] = 0.f;

#pragma unroll 4
    for (int c = 0; c < C; ++c) {
        const f32x4 xv = *(const f32x4*)(xb + (size_t)c * NN * HW);
        const float* wr = g_Wt + c * 128 + dp0;    // 16 floats: s_load_dwordx16
#pragma unroll
        for (int i = 0; i < 16; ++i) {
            const float w = wr[i];
#pragma unroll
            for (int j = 0; j < 4; ++j) acc[i][j] += w * xv[j];
        }
    }

    // output rows: row = dp0&63 within Q (half=0) or K (half=1)
    ushort_t* __restrict__ O = half ? K : Q;
    const size_t obase = ((size_t)(b * NN + n) * D + (dp0 & 63)) * HW + p;
    float s = 0.f;
#pragma unroll
    for (int i = 0; i < 16; ++i) {
        us4 o;
#pragma unroll
        for (int j = 0; j < 4; ++j) {
            s += acc[i][j] * acc[i][j];            // fp32 pre-rounding norm
            o[j] = f2bf(acc[i][j]);
        }
        *(us4*)(O + obase + (size_t)i * HW) = o;
    }
    for (int off = 32; off > 0; off >>= 1) s += __shfl_xor(s, off);
    if (ln == 0) atomicAdd((half ? kk : qq) + b * NN + n, s);
}

// ---- K2: S[n][m] += sum_f Q[n,f]*K[m,f] via one 32x32x16 bf16 MFMA tile.
// grid (F/(4*SW), B), 256 thr = 4 waves, each wave owns SW f-elems.
// SW=256 -> 1024 blocks (4/CU, 16 waves/CU) so load latency is hidden;
// the old SW=1024 ran 1 block/CU (4 waves/CU) and was latency-exposed.
// Pad rows/cols 25..31 clamp to 24: they only feed discarded output rows/cols.
__global__ void k_sqk(const ushort_t* __restrict__ Q, const ushort_t* __restrict__ K,
                      float* __restrict__ S) {
    const int t  = threadIdx.x;
    const int wv = t >> 6, ln = t & 63;
    const int b  = blockIdx.y;
    const int row  = ln & 31;
    const int rowc = (row < NN) ? row : (NN - 1);   // clamp pad rows
    const int kh   = (ln >> 5) * 8;                 // k-half offset
    const size_t f0 = (size_t)blockIdx.x * (4 * SW) + (size_t)wv * SW;
    const ushort_t* Qp = Q + ((size_t)b * NN + rowc) * F + f0 + kh;
    const ushort_t* Kp = K + ((size_t)b * NN + rowc) * F + f0 + kh;

    floatx16 acc;
#pragma unroll
    for (int r = 0; r < 16; ++r) acc[r] = 0.f;

    for (int s = 0; s < SW / 16; ++s) {
        short8 aq = *(const short8*)(Qp + s * 16);  // A[row][k] : 8 contig bf16
        short8 bk = *(const short8*)(Kp + s * 16);  // B[k][col] : K row 'col'
        acc = __builtin_amdgcn_mfma_f32_32x32x16_bf16(aq, bk, acc, 0, 0, 0);
    }

    // cross-wave reduce in LDS (stride 17 -> conflict-free), then atomics
    __shared__ float redS[4][64][17];
#pragma unroll
    for (int r = 0; r < 16; ++r) redS[wv][ln][r] = acc[r];
    __syncthreads();
    if (wv == 0) {
#pragma unroll
        for (int r = 0; r < 16; ++r) {
            float v = redS[0][ln][r] + redS[1][ln][r] + redS[2][ln][r] + redS[3][ln][r];
            const int srow = (r & 3) + 8 * (r >> 2) + 4 * (ln >> 5); // C/D: m74/m101
            const int scol = ln & 31;
            if (srow < NN && scol < NN)
                atomicAdd(&S[((size_t)b * NN + srow) * NN + scol], v);
        }
    }
}

// ---- K3: normalize logits + softmax over m; writes TRANSPOSED att.
// attT[b][m][n] so k_mix's scalar reads are contiguous. grid (B), 64 thr.
__global__ void k_softmax(const float* __restrict__ S, const float* __restrict__ qq,
                          const float* __restrict__ kk, float* __restrict__ attT) {
    const int b = blockIdx.x, n = threadIdx.x;
    if (n >= NN) return;
    const float qn = fmaxf(sqrtf(qq[b * NN + n]), 1e-12f);
    float l[NN], mx = -1e30f;
#pragma unroll
    for (int m = 0; m < NN; ++m) {
        const float km = fmaxf(sqrtf(kk[b * NN + m]), 1e-12f);
        l[m] = S[((size_t)b * NN + n) * NN + m] / (qn * km);
        mx = fmaxf(mx, l[m]);
    }
    float s = 0.f;
#pragma unroll
    for (int m = 0; m < NN; ++m) { l[m] = expf(l[m] - mx); s += l[m]; }
    const float inv = 1.f / s;
#pragma unroll
    for (int m = 0; m < NN; ++m) attT[((size_t)b * NN + m) * NN + n] = l[m] * inv;
}

// ---- K4a: xa[b,c,n,p] = sum_m att[n,m] * x[b,c,m,p], accumulator form.
// grid (HW/256, C, B). acc[25] written every m-iter -> register-resident.
__global__ void k_mix(const float* __restrict__ x, const float* __restrict__ attT,
                      float* __restrict__ xa) {
    const int p = blockIdx.x * 256 + threadIdx.x;
    const int c = blockIdx.y, b = blockIdx.z;
    const float* xb = x + ((size_t)(b * C + c) * NN) * HW + p;
    const float* at = attT + (size_t)b * NN * NN;
    float acc[NN];
#pragma unroll
    for (int n = 0; n < NN; ++n) acc[n] = 0.f;
#pragma unroll 5
    for (int m = 0; m < NN; ++m) {
        const float xm = xb[(size_t)m * HW];
#pragma unroll
        for (int n = 0; n < NN; ++n) acc[n] += at[m * NN + n] * xm; // contig s_load
    }
#pragma unroll
    for (int n = 0; n < NN; ++n)
        xa[((size_t)(b * C + c) * NN + n) * HW + p] = acc[n];
}

// ---- K4b: out[b,d,n,p] = sum_c Wv[d,c] * xa[b,c,n,p], wave-split form.
// grid (HW/256, NN, B), 4 waves; wave wv owns rows dp0=wv*16..+15, lane
// owns 4 p. acc[16][4]; W feed = one s_load_dwordx16 per c (was 64/c).
__global__ void __launch_bounds__(256, 4)
k_vproj(const float* __restrict__ xa, float* __restrict__ out) {
    const int t   = threadIdx.x;
    const int wv  = __builtin_amdgcn_readfirstlane(t >> 6);
    const int ln  = t & 63;
    const int n   = blockIdx.y, b = blockIdx.z;
    const int p   = blockIdx.x * 256 + ln * 4;
    const int dp0 = wv * 16;

    const float* xb = xa + ((size_t)(b * C) * NN + n) * HW + p;

    float acc[16][4];
#pragma unroll
    for (int i = 0; i < 16; ++i)
#pragma unroll
        for (int j = 0; j < 4; ++j) acc[i][j] = 0.f;

#pragma unroll 4
    for (int c = 0; c < C; ++c) {
        const f32x4 xv = *(const f32x4*)(xb + (size_t)c * NN * HW);
        const float* wr = g_Wvt + c * 64 + dp0;    // 16 floats: s_load_dwordx16
#pragma unroll
        for (int i = 0; i < 16; ++i) {
            const float w = wr[i];
#pragma unroll
            for (int j = 0; j < 4; ++j) acc[i][j] += w * xv[j];
        }
    }
#pragma unroll
    for (int i = 0; i < 16; ++i)
        *(f32x4*)(out + ((size_t)(b * D + dp0 + i) * NN + n) * HW + p) =
            *(const f32x4*)&acc[i][0];
}

extern "C" void kernel_launch(void* const* d_in, const int* in_sizes, int n_in,
                              void* d_out, int out_size, void* d_ws, size_t ws_size,
                              hipStream_t stream) {
    const float* x = (const float*)d_in[0];
    const float* W = (const float*)d_in[1];
    float* outf = (float*)d_out;

    // ws: [ Q bf16 52.4MB | K bf16 52.4MB ], later reused as xa fp32 (104.86MB)
    ushort_t* Q  = (ushort_t*)d_ws;
    ushort_t* K  = Q + (size_t)B * NN * F;
    float*    xa = (float*)d_ws;

    // tiny accumulators live at head of d_out (dead until k_vproj rewrites all)
    float* S    = outf;          // 4*25*25
    float* qq   = outf + 2500;   // 4*25
    float* kk   = outf + 2600;   // 4*25
    float* attT = outf + 2700;   // 4*25*25 (transposed: [b][m][n])

    k_zero   <<<dim3(11),              256, 0, stream>>>(outf);
    k_wprep  <<<dim3(48),              256, 0, stream>>>(W);
    k_qkproj <<<dim3(HW/256, NN*2, B), 256, 0, stream>>>(x, Q, K, qq, kk);
    k_sqk    <<<dim3(F/(4*SW), B),     256, 0, stream>>>(Q, K, S);
    k_softmax<<<dim3(B),                64, 0, stream>>>(S, qq, kk, attT);
    k_mix    <<<dim3(HW/256, C, B),    256, 0, stream>>>(x, attT, xa);
    k_vproj  <<<dim3(HW/256, NN, B),   256, 0, stream>>>(xa, outf);
}

// Round 2
// 343.537 us; speedup vs baseline: 1.1420x; 1.1201x over previous
//
#include <hip/hip_runtime.h>

// Problem constants (fixed by reference setup_inputs)
#define B   4
#define C   64      // input channels
#define D   64      // dims per head of q/k/v
#define NN  25      // angRes*angRes angular positions
#define HW  4096    // h*w
#define F   (D*HW)  // 262144 feature dim (d,h,w) flattened

#define SW  256     // f elems per wave in k_sqk (4 waves/block) -> 1024 blocks
#define PT  128     // p-tile per block in k_qkmfma

typedef unsigned short ushort_t;
typedef unsigned int   uint_t;
typedef __attribute__((ext_vector_type(8)))  short  short8;   // 8 bf16 (4 VGPRs)
typedef __attribute__((ext_vector_type(16))) float  floatx16; // MFMA 32x32 accum
typedef __attribute__((ext_vector_type(4)))  float  f32x4;
typedef __attribute__((ext_vector_type(4)))  unsigned short us4;

// W for q/k rows in NATIVE [d'][c] layout (d'<128), compensated bf16 split:
// W = hi + lo with |err| ~ 2^-17 rel. Wvt stays fp32 for the VALU v-path.
__device__ ushort_t g_Wthi[128 * C];
__device__ ushort_t g_Wtlo[128 * C];
__device__ float    g_Wvt[C * 64];

static __device__ __forceinline__ ushort_t f2bf(float f) {
    uint_t u = __float_as_uint(f);
    u += 0x7FFFu + ((u >> 16) & 1u);   // round-to-nearest-even
    return (ushort_t)(u >> 16);
}
static __device__ __forceinline__ float bf2f(ushort_t h) {
    return __uint_as_float((uint_t)h << 16);
}

// LDS element index for transposed x tile xT[p][c] (bf16), with c-block
// swizzle: blocks of 8 c are XOR'd by (p&7) so ds_read_b128 (8 c) and
// ds_write_b64 (4 c) stay contiguous while banks spread across p.
static __device__ __forceinline__ int lds_x(int p, int c) {
    return p * 64 + ((((c >> 3) ^ (p & 7)) << 3) | (c & 7));
}

// ---- K0: zero the S/qq/kk accumulators (they live at head of d_out) ----
__global__ void k_zero(float* acc) {
    int i = blockIdx.x * 256 + threadIdx.x;
    if (i < 2700) acc[i] = 0.f;   // S 2500 + qq 100 + kk 100
}

// ---- Kw: split W rows 0..127 into bf16 hi/lo (native layout) + Wv^T. ----
__global__ void k_wprep(const float* __restrict__ W) {
    int i = blockIdx.x * 256 + threadIdx.x;          // over 192*64
    if (i < 128 * 64) {
        float w = W[i];                              // W[d'][c], native index
        ushort_t hi = f2bf(w);
        g_Wthi[i] = hi;
        g_Wtlo[i] = f2bf(w - bf2f(hi));
    } else if (i < 192 * 64) {
        int j = i - 128 * 64;
        int d = j >> 6, c = j & 63;
        g_Wvt[c * 64 + d] = W[(128 + d) * 64 + c];
    }
}

// ---- K1: Q,K projection via compensated-bf16 MFMA + fused norms.
// grid (HW/PT, NN, B), 256 thr = 4 waves. Per block: stage x[64c][PTp]
// into LDS transposed (hi/lo bf16), then wave wv computes the 32-row
// d'-slab d0=wv*32 of [Q;K] for all PT p: 4 p-tiles x (4 k-steps x 3
// hi/lo combos) = 48 MFMA. Result == fp32 projection to ~2^-17, then
// f2bf-rounded exactly like the old VALU kernel. Norms summed pre-round.
__global__ void __launch_bounds__(256, 2)
k_qkmfma(const float* __restrict__ x,
         ushort_t* __restrict__ Q, ushort_t* __restrict__ K,
         float* __restrict__ qq, float* __restrict__ kk) {
    __shared__ ushort_t sXhi[PT * 64];
    __shared__ ushort_t sXlo[PT * 64];

    const int t  = threadIdx.x;
    const int wv = t >> 6, ln = t & 63;
    const int n  = blockIdx.y, b = blockIdx.z;
    const int gp0 = blockIdx.x * PT;

    // ---- stage: wave wv loads c in [wv*16, wv*16+16), converts to hi/lo,
    // writes transposed into LDS. Global loads: 64 lanes x 4B contiguous.
    {
        const int c16 = wv * 16;
#pragma unroll
        for (int cg = 0; cg < 4; ++cg) {
            const int c4 = c16 + cg * 4;
            const float* xc = x + ((size_t)(b * C + c4) * NN + n) * HW + gp0;
#pragma unroll
            for (int ph = 0; ph < 2; ++ph) {
                const int p = ph * 64 + ln;
                float v[4];
#pragma unroll
                for (int i = 0; i < 4; ++i) v[i] = xc[(size_t)i * NN * HW + p];
                us4 h, l;
#pragma unroll
                for (int i = 0; i < 4; ++i) {
                    ushort_t hi = f2bf(v[i]);
                    h[i] = hi;
                    l[i] = f2bf(v[i] - bf2f(hi));
                }
                *(us4*)&sXhi[lds_x(p, c4)] = h;
                *(us4*)&sXlo[lds_x(p, c4)] = l;
            }
        }
    }
    __syncthreads();

    // ---- A fragments: W rows d0..d0+31, straight from global (L2-hot).
    const int row = ln & 31, kh = (ln >> 5) * 8, d0 = wv * 32;
    short8 ahi[4], alo[4];
#pragma unroll
    for (int ks = 0; ks < 4; ++ks) {
        ahi[ks] = *(const short8*)&g_Wthi[(d0 + row) * 64 + ks * 16 + kh];
        alo[ks] = *(const short8*)&g_Wtlo[(d0 + row) * 64 + ks * 16 + kh];
    }

    ushort_t* __restrict__ O = (wv < 2) ? Q : K;
    const int dbase = (wv < 2) ? d0 : (d0 - 64);
    const size_t obase = ((size_t)(b * NN + n) * D + dbase) * HW + gp0;

    float nrm = 0.f;
#pragma unroll
    for (int pt = 0; pt < 4; ++pt) {
        const int pcol = pt * 32 + (ln & 31);
        floatx16 acc;
#pragma unroll
        for (int r = 0; r < 16; ++r) acc[r] = 0.f;
#pragma unroll
        for (int ks = 0; ks < 4; ++ks) {
            const int c0 = ks * 16 + kh;
            short8 bhi = *(const short8*)&sXhi[lds_x(pcol, c0)];
            short8 blo = *(const short8*)&sXlo[lds_x(pcol, c0)];
            acc = __builtin_amdgcn_mfma_f32_32x32x16_bf16(ahi[ks], bhi, acc, 0, 0, 0);
            acc = __builtin_amdgcn_mfma_f32_32x32x16_bf16(alo[ks], bhi, acc, 0, 0, 0);
            acc = __builtin_amdgcn_mfma_f32_32x32x16_bf16(ahi[ks], blo, acc, 0, 0, 0);
        }
        // C/D layout (m74/m101): col = ln&31, row = (r&3)+8*(r>>2)+4*(ln>>5)
#pragma unroll
        for (int r = 0; r < 16; ++r) {
            const int dr = (r & 3) + 8 * (r >> 2) + 4 * (ln >> 5);
            nrm += acc[r] * acc[r];
            O[obase + (size_t)dr * HW + pcol] = f2bf(acc[r]);
        }
    }
    for (int off = 32; off > 0; off >>= 1) nrm += __shfl_xor(nrm, off);
    if (ln == 0) atomicAdd(((wv < 2) ? qq : kk) + b * NN + n, nrm);
}

// ---- K2: S[n][m] += sum_f Q[n,f]*K[m,f] via one 32x32x16 bf16 MFMA tile.
// grid (F/(4*SW), B), 256 thr = 4 waves, each wave owns SW f-elems.
__global__ void k_sqk(const ushort_t* __restrict__ Q, const ushort_t* __restrict__ K,
                      float* __restrict__ S) {
    const int t  = threadIdx.x;
    const int wv = t >> 6, ln = t & 63;
    const int b  = blockIdx.y;
    const int row  = ln & 31;
    const int rowc = (row < NN) ? row : (NN - 1);   // clamp pad rows
    const int kh   = (ln >> 5) * 8;                 // k-half offset
    const size_t f0 = (size_t)blockIdx.x * (4 * SW) + (size_t)wv * SW;
    const ushort_t* Qp = Q + ((size_t)b * NN + rowc) * F + f0 + kh;
    const ushort_t* Kp = K + ((size_t)b * NN + rowc) * F + f0 + kh;

    floatx16 acc;
#pragma unroll
    for (int r = 0; r < 16; ++r) acc[r] = 0.f;

    for (int s = 0; s < SW / 16; ++s) {
        short8 aq = *(const short8*)(Qp + s * 16);  // A[row][k] : 8 contig bf16
        short8 bk = *(const short8*)(Kp + s * 16);  // B[k][col] : K row 'col'
        acc = __builtin_amdgcn_mfma_f32_32x32x16_bf16(aq, bk, acc, 0, 0, 0);
    }

    // cross-wave reduce in LDS (stride 17 -> conflict-free), then atomics
    __shared__ float redS[4][64][17];
#pragma unroll
    for (int r = 0; r < 16; ++r) redS[wv][ln][r] = acc[r];
    __syncthreads();
    if (wv == 0) {
#pragma unroll
        for (int r = 0; r < 16; ++r) {
            float v = redS[0][ln][r] + redS[1][ln][r] + redS[2][ln][r] + redS[3][ln][r];
            const int srow = (r & 3) + 8 * (r >> 2) + 4 * (ln >> 5); // C/D: m74/m101
            const int scol = ln & 31;
            if (srow < NN && scol < NN)
                atomicAdd(&S[((size_t)b * NN + srow) * NN + scol], v);
        }
    }
}

// ---- K3: normalize logits + softmax over m; writes TRANSPOSED att.
__global__ void k_softmax(const float* __restrict__ S, const float* __restrict__ qq,
                          const float* __restrict__ kk, float* __restrict__ attT) {
    const int b = blockIdx.x, n = threadIdx.x;
    if (n >= NN) return;
    const float qn = fmaxf(sqrtf(qq[b * NN + n]), 1e-12f);
    float l[NN], mx = -1e30f;
#pragma unroll
    for (int m = 0; m < NN; ++m) {
        const float km = fmaxf(sqrtf(kk[b * NN + m]), 1e-12f);
        l[m] = S[((size_t)b * NN + n) * NN + m] / (qn * km);
        mx = fmaxf(mx, l[m]);
    }
    float s = 0.f;
#pragma unroll
    for (int m = 0; m < NN; ++m) { l[m] = expf(l[m] - mx); s += l[m]; }
    const float inv = 1.f / s;
#pragma unroll
    for (int m = 0; m < NN; ++m) attT[((size_t)b * NN + m) * NN + n] = l[m] * inv;
}

// ---- K4a: xa[b,c,n,p] = sum_m att[n,m] * x[b,c,m,p], accumulator form.
__global__ void k_mix(const float* __restrict__ x, const float* __restrict__ attT,
                      float* __restrict__ xa) {
    const int p = blockIdx.x * 256 + threadIdx.x;
    const int c = blockIdx.y, b = blockIdx.z;
    const float* xb = x + ((size_t)(b * C + c) * NN) * HW + p;
    const float* at = attT + (size_t)b * NN * NN;
    float acc[NN];
#pragma unroll
    for (int n = 0; n < NN; ++n) acc[n] = 0.f;
#pragma unroll 5
    for (int m = 0; m < NN; ++m) {
        const float xm = xb[(size_t)m * HW];
#pragma unroll
        for (int n = 0; n < NN; ++n) acc[n] += at[m * NN + n] * xm; // contig s_load
    }
#pragma unroll
    for (int n = 0; n < NN; ++n)
        xa[((size_t)(b * C + c) * NN + n) * HW + p] = acc[n];
}

// ---- K4b: out[b,d,n,p] = sum_c Wv[d,c] * xa[b,c,n,p], wave-split form.
__global__ void __launch_bounds__(256, 4)
k_vproj(const float* __restrict__ xa, float* __restrict__ out) {
    const int t   = threadIdx.x;
    const int wv  = __builtin_amdgcn_readfirstlane(t >> 6);
    const int ln  = t & 63;
    const int n   = blockIdx.y, b = blockIdx.z;
    const int p   = blockIdx.x * 256 + ln * 4;
    const int dp0 = wv * 16;

    const float* xb = xa + ((size_t)(b * C) * NN + n) * HW + p;

    float acc[16][4];
#pragma unroll
    for (int i = 0; i < 16; ++i)
#pragma unroll
        for (int j = 0; j < 4; ++j) acc[i][j] = 0.f;

#pragma unroll 4
    for (int c = 0; c < C; ++c) {
        const f32x4 xv = *(const f32x4*)(xb + (size_t)c * NN * HW);
        const float* wr = g_Wvt + c * 64 + dp0;    // 16 floats: s_load_dwordx16
#pragma unroll
        for (int i = 0; i < 16; ++i) {
            const float w = wr[i];
#pragma unroll
            for (int j = 0; j < 4; ++j) acc[i][j] += w * xv[j];
        }
    }
#pragma unroll
    for (int i = 0; i < 16; ++i)
        *(f32x4*)(out + ((size_t)(b * D + dp0 + i) * NN + n) * HW + p) =
            *(const f32x4*)&acc[i][0];
}

extern "C" void kernel_launch(void* const* d_in, const int* in_sizes, int n_in,
                              void* d_out, int out_size, void* d_ws, size_t ws_size,
                              hipStream_t stream) {
    const float* x = (const float*)d_in[0];
    const float* W = (const float*)d_in[1];
    float* outf = (float*)d_out;

    // ws: [ Q bf16 52.4MB | K bf16 52.4MB ], later reused as xa fp32 (104.86MB)
    ushort_t* Q  = (ushort_t*)d_ws;
    ushort_t* K  = Q + (size_t)B * NN * F;
    float*    xa = (float*)d_ws;

    // tiny accumulators live at head of d_out (dead until k_vproj rewrites all)
    float* S    = outf;          // 4*25*25
    float* qq   = outf + 2500;   // 4*25
    float* kk   = outf + 2600;   // 4*25
    float* attT = outf + 2700;   // 4*25*25 (transposed: [b][m][n])

    k_zero   <<<dim3(11),             256, 0, stream>>>(outf);
    k_wprep  <<<dim3(48),             256, 0, stream>>>(W);
    k_qkmfma <<<dim3(HW/PT, NN, B),   256, 0, stream>>>(x, Q, K, qq, kk);
    k_sqk    <<<dim3(F/(4*SW), B),    256, 0, stream>>>(Q, K, S);
    k_softmax<<<dim3(B),               64, 0, stream>>>(S, qq, kk, attT);
    k_mix    <<<dim3(HW/256, C, B),   256, 0, stream>>>(x, attT, xa);
    k_vproj  <<<dim3(HW/256, NN, B),  256, 0, stream>>>(xa, outf);
}